// Round 1
// baseline (742.659 us; speedup 1.0000x reference)
//
#include <hip/hip_runtime.h>

#define THREADS 256

// ---------- degree / counts ----------
__global__ void k_init(float* __restrict__ deg, int* __restrict__ counts, int n) {
    int i = blockIdx.x * THREADS + threadIdx.x;
    if (i < n) { deg[i] = 1.0f; counts[i] = 0; }   // self-loop weight 1 pre-added
}

__global__ void k_count(const int* __restrict__ ei, const float* __restrict__ ew,
                        float* __restrict__ deg, int* __restrict__ counts, int E) {
    int e = blockIdx.x * THREADS + threadIdx.x;
    if (e >= E) return;
    int c = ei[E + e];                 // edge_index[1][e] = destination
    atomicAdd(&deg[c], ew[e]);
    atomicAdd(&counts[c], 1);
}

__global__ void k_dinv(float* __restrict__ deg, int n) {
    int i = blockIdx.x * THREADS + threadIdx.x;
    if (i < n) { float d = deg[i]; deg[i] = d > 0.f ? rsqrtf(d) : 0.f; }
}

// ---------- exclusive prefix scan over counts (3-kernel hierarchical) ----------
__global__ void k_scan_part(const int* __restrict__ counts, int* __restrict__ offsets,
                            int* __restrict__ blocksum, int n) {
    __shared__ int s[THREADS];
    int i = blockIdx.x * THREADS + threadIdx.x;
    int v = (i < n) ? counts[i] : 0;
    s[threadIdx.x] = v;
    __syncthreads();
    for (int d = 1; d < THREADS; d <<= 1) {
        int t = (threadIdx.x >= d) ? s[threadIdx.x - d] : 0;
        __syncthreads();
        s[threadIdx.x] += t;
        __syncthreads();
    }
    if (i < n) offsets[i] = s[threadIdx.x] - v;          // exclusive
    if (threadIdx.x == THREADS - 1) blocksum[blockIdx.x] = s[THREADS - 1];
}

__global__ void k_scan_block(int* __restrict__ blocksum, int nb) {
    __shared__ int s[THREADS];
    int v = (threadIdx.x < nb) ? blocksum[threadIdx.x] : 0;
    s[threadIdx.x] = v;
    __syncthreads();
    for (int d = 1; d < THREADS; d <<= 1) {
        int t = (threadIdx.x >= d) ? s[threadIdx.x - d] : 0;
        __syncthreads();
        s[threadIdx.x] += t;
        __syncthreads();
    }
    if (threadIdx.x < nb) blocksum[threadIdx.x] = s[threadIdx.x] - v;  // exclusive
}

__global__ void k_scan_add(int* __restrict__ offsets, const int* __restrict__ blocksum,
                           int* __restrict__ cursor, int n) {
    int i = blockIdx.x * THREADS + threadIdx.x;
    if (i >= n) return;
    int o = offsets[i] + blocksum[blockIdx.x];
    offsets[i] = o;
    cursor[i]  = o;
}

// ---------- CSR fill (grouped by destination) with precomputed norm ----------
__global__ void k_fill(const int* __restrict__ ei, const float* __restrict__ ew,
                       const float* __restrict__ dinv, int* __restrict__ cursor,
                       int* __restrict__ esrc, float* __restrict__ enorm, int E) {
    int e = blockIdx.x * THREADS + threadIdx.x;
    if (e >= E) return;
    int r = ei[e];
    int c = ei[E + e];
    int pos = atomicAdd(&cursor[c], 1);
    esrc[pos]  = r;
    enorm[pos] = dinv[r] * ew[e] * dinv[c];
}

// ---------- aggregation: out[i] = dinv[i]^2 * feat[i] + sum_e norm_e * feat[src_e]
// one wave (64 lanes) per node; lane l covers float4 chunk l (256 features)
__global__ void k_agg(const float* __restrict__ feat,
                      const int* __restrict__ eoff, const int* __restrict__ ecnt,
                      const int* __restrict__ esrc, const float* __restrict__ enorm,
                      const float* __restrict__ dinv,
                      float* __restrict__ out, int n) {
    int wave = threadIdx.x >> 6;
    int lane = threadIdx.x & 63;
    int node = blockIdx.x * 4 + wave;
    if (node >= n) return;
    const float4* f4 = (const float4*)feat;
    float ds = dinv[node];
    ds = ds * ds;                       // self-loop norm: dinv*1*dinv
    float4 v = f4[node * 64 + lane];
    float4 acc;
    acc.x = ds * v.x; acc.y = ds * v.y; acc.z = ds * v.z; acc.w = ds * v.w;
    int off = eoff[node];
    int end = off + ecnt[node];
    for (int e = off; e < end; e++) {
        int s   = esrc[e];
        float w = enorm[e];
        float4 u = f4[s * 64 + lane];
        acc.x += w * u.x; acc.y += w * u.y; acc.z += w * u.z; acc.w += w * u.w;
    }
    ((float4*)out)[node * 64 + lane] = acc;
}

// ---------- f32 tiled GEMM: C[M x Nc] = A[M x K] @ B[K x Nc] + bias, optional relu
#define TM 64
#define TN 64
#define KB 16
__global__ void k_gemm(const float* __restrict__ A, const float* __restrict__ B,
                       const float* __restrict__ bias, float* __restrict__ C,
                       int M, int K, int Nc, int relu) {
    __shared__ float As[TM][KB + 1];
    __shared__ float Bs[KB][TN];
    int tx = threadIdx.x, ty = threadIdx.y;
    int tid = ty * 16 + tx;
    int row0 = blockIdx.y * TM;
    int col0 = blockIdx.x * TN;
    float acc[4][4] = {};
    for (int k0 = 0; k0 < K; k0 += KB) {
        #pragma unroll
        for (int i = 0; i < 4; i++) {
            int idx = tid + i * 256;           // 0..1023
            int r = idx / KB, kk = idx % KB;
            int gr = row0 + r;
            As[r][kk] = (gr < M) ? A[gr * K + k0 + kk] : 0.f;
        }
        #pragma unroll
        for (int i = 0; i < 4; i++) {
            int idx = tid + i * 256;
            int kk = idx / TN, c = idx % TN;
            Bs[kk][c] = B[(k0 + kk) * Nc + col0 + c];
        }
        __syncthreads();
        #pragma unroll
        for (int kk = 0; kk < KB; kk++) {
            float a[4], b[4];
            #pragma unroll
            for (int i = 0; i < 4; i++) a[i] = As[ty * 4 + i][kk];
            #pragma unroll
            for (int j = 0; j < 4; j++) b[j] = Bs[kk][tx * 4 + j];
            #pragma unroll
            for (int i = 0; i < 4; i++)
                #pragma unroll
                for (int j = 0; j < 4; j++) acc[i][j] += a[i] * b[j];
        }
        __syncthreads();
    }
    #pragma unroll
    for (int i = 0; i < 4; i++) {
        int gr = row0 + ty * 4 + i;
        if (gr >= M) continue;
        #pragma unroll
        for (int j = 0; j < 4; j++) {
            int gc = col0 + tx * 4 + j;
            float v = acc[i][j] + bias[gc];
            if (relu) v = fmaxf(v, 0.f);
            C[gr * Nc + gc] = v;
        }
    }
}

extern "C" void kernel_launch(void* const* d_in, const int* in_sizes, int n_in,
                              void* d_out, int out_size, void* d_ws, size_t ws_size,
                              hipStream_t stream) {
    const float* x   = (const float*)d_in[0];
    const int*   ei  = (const int*)d_in[1];
    const float* ew  = (const float*)d_in[2];
    const float* W1  = (const float*)d_in[3];
    const float* b1  = (const float*)d_in[4];
    const float* Wmu = (const float*)d_in[5];
    const float* bmu = (const float*)d_in[6];
    const float* Wls = (const float*)d_in[7];
    const float* bls = (const float*)d_in[8];

    const int DIN = 256, DH = 256, DOUT = 128;
    const int N = in_sizes[0] / DIN;
    const int E = in_sizes[2];

    // workspace layout (all 16B-aligned given 4B elements and sizes % 4 == 0)
    float* deg      = (float*)d_ws;              // N
    int*   counts   = (int*)(deg + N);           // N
    int*   offsets  = counts + N;                // N
    int*   cursor   = offsets + N;               // N
    int*   blocksum = cursor + N;                // <= 256
    int*   esrc     = blocksum + 256;            // E
    float* enorm    = (float*)(esrc + E);        // E
    float* bufA     = enorm + E;                 // N*256 (Agg1, reused as Agg2)
    float* bufH     = bufA + (size_t)N * DH;     // N*256 (h)

    float* out_mu = (float*)d_out;
    float* out_ls = out_mu + (size_t)N * DOUT;

    int gN = (N + THREADS - 1) / THREADS;    // 196
    int gE = (E + THREADS - 1) / THREADS;

    k_init<<<gN, THREADS, 0, stream>>>(deg, counts, N);
    k_count<<<gE, THREADS, 0, stream>>>(ei, ew, deg, counts, E);
    k_dinv<<<gN, THREADS, 0, stream>>>(deg, N);   // deg now holds dinv

    k_scan_part<<<gN, THREADS, 0, stream>>>(counts, offsets, blocksum, N);
    k_scan_block<<<1, THREADS, 0, stream>>>(blocksum, gN);
    k_scan_add<<<gN, THREADS, 0, stream>>>(offsets, blocksum, cursor, N);

    k_fill<<<gE, THREADS, 0, stream>>>(ei, ew, deg, cursor, esrc, enorm, E);

    // layer 1: Agg1 = A_hat @ x ; h = relu(Agg1 @ W1 + b1)
    int gAgg = (N + 3) / 4;
    k_agg<<<gAgg, THREADS, 0, stream>>>(x, offsets, counts, esrc, enorm, deg, bufA, N);
    dim3 blk(16, 16);
    dim3 g1(DH / TN, (N + TM - 1) / TM);
    k_gemm<<<g1, blk, 0, stream>>>(bufA, W1, b1, bufH, N, DIN, DH, 1);

    // layer 2: Agg2 = A_hat @ h ; mu / logstd GEMMs
    k_agg<<<gAgg, THREADS, 0, stream>>>(bufH, offsets, counts, esrc, enorm, deg, bufA, N);
    dim3 g2(DOUT / TN, (N + TM - 1) / TM);
    k_gemm<<<g2, blk, 0, stream>>>(bufA, Wmu, bmu, out_mu, N, DH, DOUT, 0);
    k_gemm<<<g2, blk, 0, stream>>>(bufA, Wls, bls, out_ls, N, DH, DOUT, 0);
}

// Round 2
// 436.765 us; speedup vs baseline: 1.7004x; 1.7004x over previous
//
#include <hip/hip_runtime.h>

#define THREADS 256

typedef __attribute__((ext_vector_type(8))) short bf16x8;
typedef __attribute__((ext_vector_type(4))) float f32x4;

__device__ inline float bf2f(unsigned short u) {
    union { unsigned int i; float f; } v; v.i = ((unsigned int)u) << 16; return v.f;
}
__device__ inline unsigned short f2bf(float f) {
    union { float f; unsigned int i; } v; v.f = f;
    unsigned int i = v.i;
    i += 0x7fff + ((i >> 16) & 1);   // round-to-nearest-even
    return (unsigned short)(i >> 16);
}

// ---------- degree / counts ----------
__global__ void k_init(float* __restrict__ deg, int* __restrict__ counts, int n) {
    int i = blockIdx.x * THREADS + threadIdx.x;
    if (i < n) { deg[i] = 1.0f; counts[i] = 0; }   // self-loop weight 1 pre-added
}

__global__ void k_count(const int* __restrict__ ei, const float* __restrict__ ew,
                        float* __restrict__ deg, int* __restrict__ counts, int E) {
    int e = blockIdx.x * THREADS + threadIdx.x;
    if (e >= E) return;
    int c = ei[E + e];                 // destination
    atomicAdd(&deg[c], ew[e]);
    atomicAdd(&counts[c], 1);
}

__global__ void k_dinv(float* __restrict__ deg, int n) {
    int i = blockIdx.x * THREADS + threadIdx.x;
    if (i < n) { float d = deg[i]; deg[i] = d > 0.f ? rsqrtf(d) : 0.f; }
}

// ---------- exclusive prefix scan over counts ----------
__global__ void k_scan_part(const int* __restrict__ counts, int* __restrict__ offsets,
                            int* __restrict__ blocksum, int n) {
    __shared__ int s[THREADS];
    int i = blockIdx.x * THREADS + threadIdx.x;
    int v = (i < n) ? counts[i] : 0;
    s[threadIdx.x] = v;
    __syncthreads();
    for (int d = 1; d < THREADS; d <<= 1) {
        int t = (threadIdx.x >= d) ? s[threadIdx.x - d] : 0;
        __syncthreads();
        s[threadIdx.x] += t;
        __syncthreads();
    }
    if (i < n) offsets[i] = s[threadIdx.x] - v;
    if (threadIdx.x == THREADS - 1) blocksum[blockIdx.x] = s[THREADS - 1];
}

__global__ void k_scan_block(int* __restrict__ blocksum, int nb) {
    __shared__ int s[THREADS];
    int v = (threadIdx.x < nb) ? blocksum[threadIdx.x] : 0;
    s[threadIdx.x] = v;
    __syncthreads();
    for (int d = 1; d < THREADS; d <<= 1) {
        int t = (threadIdx.x >= d) ? s[threadIdx.x - d] : 0;
        __syncthreads();
        s[threadIdx.x] += t;
        __syncthreads();
    }
    if (threadIdx.x < nb) blocksum[threadIdx.x] = s[threadIdx.x] - v;
}

__global__ void k_scan_add(int* __restrict__ offsets, const int* __restrict__ blocksum,
                           int* __restrict__ cursor, int n) {
    int i = blockIdx.x * THREADS + threadIdx.x;
    if (i >= n) return;
    int o = offsets[i] + blocksum[blockIdx.x];
    offsets[i] = o;
    cursor[i]  = o;
}

// ---------- CSR fill: epack[pos] = {src, float_bits(norm)} ----------
__global__ void k_fill(const int* __restrict__ ei, const float* __restrict__ ew,
                       const float* __restrict__ dinv, int* __restrict__ cursor,
                       int2* __restrict__ epack, int E) {
    int e = blockIdx.x * THREADS + threadIdx.x;
    if (e >= E) return;
    int r = ei[e];
    int c = ei[E + e];
    int pos = atomicAdd(&cursor[c], 1);
    int2 m; m.x = r; m.y = __float_as_int(dinv[r] * ew[e] * dinv[c]);
    epack[pos] = m;
}

// ---------- f32 -> bf16 conversion of x (4 elements/thread) ----------
__global__ void k_cvt_x(const float4* __restrict__ x, ushort4* __restrict__ xb, int n4) {
    int i = blockIdx.x * THREADS + threadIdx.x;
    if (i >= n4) return;
    float4 v = x[i];
    ushort4 o;
    o.x = f2bf(v.x); o.y = f2bf(v.y); o.z = f2bf(v.z); o.w = f2bf(v.w);
    xb[i] = o;
}

// ---------- weight prep: transpose+cvt W1 -> W1t[n][k]; concat [Wmu|Wls] -> Wct[n][k]; bcat
__global__ void k_cvt_w(const float* __restrict__ W1, const float* __restrict__ Wmu,
                        const float* __restrict__ Wls, const float* __restrict__ bmu,
                        const float* __restrict__ bls,
                        ushort* __restrict__ W1t, ushort* __restrict__ Wct,
                        float* __restrict__ bcat) {
    int n = blockIdx.x, k = threadIdx.x;
    if (n < 256) {
        W1t[n * 256 + k] = f2bf(W1[k * 256 + n]);
    } else if (n < 512) {
        int nn = n - 256;
        float v = (nn < 128) ? Wmu[k * 128 + nn] : Wls[k * 128 + (nn - 128)];
        Wct[nn * 256 + k] = f2bf(v);
    } else {
        bcat[k] = (k < 128) ? bmu[k] : bls[k - 128];
    }
}

// ---------- aggregation (bf16 in / bf16 out, f32 accumulate) ----------
// one wave per node; lane covers 4 features (8 B); unroll 4 for MLP
__global__ void k_agg(const ushort4* __restrict__ fb,
                      const int* __restrict__ eoff, const int* __restrict__ ecnt,
                      const int2* __restrict__ epack, const float* __restrict__ dinv,
                      ushort4* __restrict__ outb, int n) {
    int wave = threadIdx.x >> 6, lane = threadIdx.x & 63;
    int node = blockIdx.x * 4 + wave;
    if (node >= n) return;
    float ds = dinv[node]; ds *= ds;        // self-loop norm
    ushort4 v = fb[node * 64 + lane];
    float ax = ds * bf2f(v.x), ay = ds * bf2f(v.y),
          az = ds * bf2f(v.z), aw = ds * bf2f(v.w);
    int e = eoff[node], end = e + ecnt[node];
    for (; e + 4 <= end; e += 4) {
        int2 m0 = epack[e], m1 = epack[e + 1], m2 = epack[e + 2], m3 = epack[e + 3];
        ushort4 u0 = fb[m0.x * 64 + lane];
        ushort4 u1 = fb[m1.x * 64 + lane];
        ushort4 u2 = fb[m2.x * 64 + lane];
        ushort4 u3 = fb[m3.x * 64 + lane];
        float w0 = __int_as_float(m0.y), w1 = __int_as_float(m1.y),
              w2 = __int_as_float(m2.y), w3 = __int_as_float(m3.y);
        ax += w0 * bf2f(u0.x) + w1 * bf2f(u1.x) + w2 * bf2f(u2.x) + w3 * bf2f(u3.x);
        ay += w0 * bf2f(u0.y) + w1 * bf2f(u1.y) + w2 * bf2f(u2.y) + w3 * bf2f(u3.y);
        az += w0 * bf2f(u0.z) + w1 * bf2f(u1.z) + w2 * bf2f(u2.z) + w3 * bf2f(u3.z);
        aw += w0 * bf2f(u0.w) + w1 * bf2f(u1.w) + w2 * bf2f(u2.w) + w3 * bf2f(u3.w);
    }
    for (; e < end; e++) {
        int2 m = epack[e];
        ushort4 u = fb[m.x * 64 + lane];
        float w = __int_as_float(m.y);
        ax += w * bf2f(u.x); ay += w * bf2f(u.y);
        az += w * bf2f(u.z); aw += w * bf2f(u.w);
    }
    ushort4 o;
    o.x = f2bf(ax); o.y = f2bf(ay); o.z = f2bf(az); o.w = f2bf(aw);
    outb[node * 64 + lane] = o;
}

// ---------- bf16 MFMA GEMM: C = A[MxK] @ Bt[NxK]^T + bias
// K=256, N=256 fixed. mode 0: relu -> bf16 Cb. mode 1: f32 split to Cmu/Cls.
#define LDT 40   // padded LDS row stride (ushorts): 80B -> <=2-way bank aliasing
__global__ __launch_bounds__(256) void k_gemm(const ushort* __restrict__ A,
        const ushort* __restrict__ Bt, const float* __restrict__ bias,
        ushort* __restrict__ Cb, float* __restrict__ Cmu, float* __restrict__ Cls,
        int M, int mode) {
    __shared__ ushort As[128 * LDT];
    __shared__ ushort Bs[128 * LDT];
    int tid = threadIdx.x;
    int lane = tid & 63, wave = tid >> 6;
    int row0 = blockIdx.y * 128, col0 = blockIdx.x * 128;
    int mw = (wave >> 1) * 64, nw = (wave & 1) * 64;
    int lr = lane & 15, lq = lane >> 4;
    f32x4 acc[4][4] = {};
    for (int k0 = 0; k0 < 256; k0 += 32) {
        #pragma unroll
        for (int i = 0; i < 2; i++) {
            int c = tid + i * 256;          // 0..511 chunks of 8 bf16
            int r = c >> 2, q = c & 3;
            int gr = row0 + r;
            int4 av = make_int4(0, 0, 0, 0);
            if (gr < M) av = *(const int4*)(A + (size_t)gr * 256 + k0 + q * 8);
            *(int4*)(&As[r * LDT + q * 8]) = av;
            int4 bv = *(const int4*)(Bt + (size_t)(col0 + r) * 256 + k0 + q * 8);
            *(int4*)(&Bs[r * LDT + q * 8]) = bv;
        }
        __syncthreads();
        bf16x8 af[4], bfr[4];
        #pragma unroll
        for (int mi = 0; mi < 4; mi++)
            af[mi] = *(const bf16x8*)(&As[(mw + mi * 16 + lr) * LDT + lq * 8]);
        #pragma unroll
        for (int ni = 0; ni < 4; ni++)
            bfr[ni] = *(const bf16x8*)(&Bs[(nw + ni * 16 + lr) * LDT + lq * 8]);
        #pragma unroll
        for (int mi = 0; mi < 4; mi++)
            #pragma unroll
            for (int ni = 0; ni < 4; ni++)
                acc[mi][ni] = __builtin_amdgcn_mfma_f32_16x16x32_bf16(
                    af[mi], bfr[ni], acc[mi][ni], 0, 0, 0);
        __syncthreads();
    }
    // epilogue: C/D layout col=lane&15, row=(lane>>4)*4+reg
    #pragma unroll
    for (int mi = 0; mi < 4; mi++) {
        #pragma unroll
        for (int ni = 0; ni < 4; ni++) {
            #pragma unroll
            for (int r = 0; r < 4; r++) {
                int grow = row0 + mw + mi * 16 + lq * 4 + r;
                int gcol = col0 + nw + ni * 16 + lr;
                if (grow < M) {
                    float val = acc[mi][ni][r] + bias[gcol];
                    if (mode == 0) {
                        val = fmaxf(val, 0.f);
                        Cb[(size_t)grow * 256 + gcol] = f2bf(val);
                    } else {
                        if (gcol < 128) Cmu[(size_t)grow * 128 + gcol] = val;
                        else            Cls[(size_t)grow * 128 + (gcol - 128)] = val;
                    }
                }
            }
        }
    }
}

extern "C" void kernel_launch(void* const* d_in, const int* in_sizes, int n_in,
                              void* d_out, int out_size, void* d_ws, size_t ws_size,
                              hipStream_t stream) {
    const float* x   = (const float*)d_in[0];
    const int*   ei  = (const int*)d_in[1];
    const float* ew  = (const float*)d_in[2];
    const float* W1  = (const float*)d_in[3];
    const float* b1  = (const float*)d_in[4];
    const float* Wmu = (const float*)d_in[5];
    const float* bmu = (const float*)d_in[6];
    const float* Wls = (const float*)d_in[7];
    const float* bls = (const float*)d_in[8];

    const int DIN = 256, DOUT = 128;
    const int N = in_sizes[0] / DIN;
    const int E = in_sizes[2];

    // workspace layout
    float* deg      = (float*)d_ws;                   // N
    int*   counts   = (int*)(deg + N);                // N
    int*   offsets  = counts + N;                     // N
    int*   cursor   = offsets + N;                    // N
    int*   blocksum = cursor + N;                     // 256
    int2*  epack    = (int2*)(blocksum + 256);        // E
    ushort* xb      = (ushort*)(epack + E);           // N*256
    ushort* agg     = xb + (size_t)N * 256;           // N*256 (Agg1b / Agg2b)
    ushort* hb      = agg + (size_t)N * 256;          // N*256
    ushort* W1t     = hb + (size_t)N * 256;           // 256*256
    ushort* Wct     = W1t + 256 * 256;                // 256*256
    float*  bcat    = (float*)(Wct + 256 * 256);      // 256

    float* out_mu = (float*)d_out;
    float* out_ls = out_mu + (size_t)N * DOUT;

    int gN = (N + THREADS - 1) / THREADS;
    int gE = (E + THREADS - 1) / THREADS;

    k_init<<<gN, THREADS, 0, stream>>>(deg, counts, N);
    k_count<<<gE, THREADS, 0, stream>>>(ei, ew, deg, counts, E);
    k_dinv<<<gN, THREADS, 0, stream>>>(deg, N);   // deg now holds dinv

    k_scan_part<<<gN, THREADS, 0, stream>>>(counts, offsets, blocksum, N);
    k_scan_block<<<1, THREADS, 0, stream>>>(blocksum, gN);
    k_scan_add<<<gN, THREADS, 0, stream>>>(offsets, blocksum, cursor, N);

    k_fill<<<gE, THREADS, 0, stream>>>(ei, ew, deg, cursor, epack, E);

    k_cvt_x<<<(N * 64 + THREADS - 1) / THREADS, THREADS, 0, stream>>>(
        (const float4*)x, (ushort4*)xb, N * 64);
    k_cvt_w<<<513, THREADS, 0, stream>>>(W1, Wmu, Wls, bmu, bls, W1t, Wct, bcat);

    int gAgg = (N + 3) / 4;
    dim3 ggrid(2, (N + 127) / 128);

    // layer 1
    k_agg<<<gAgg, THREADS, 0, stream>>>((const ushort4*)xb, offsets, counts,
                                        epack, deg, (ushort4*)agg, N);
    k_gemm<<<ggrid, 256, 0, stream>>>(agg, W1t, b1, hb, nullptr, nullptr, N, 0);

    // layer 2 (mu & logstd fused: Wct = [Wmu|Wls]^T)
    k_agg<<<gAgg, THREADS, 0, stream>>>((const ushort4*)hb, offsets, counts,
                                        epack, deg, (ushort4*)agg, N);
    k_gemm<<<ggrid, 256, 0, stream>>>(agg, Wct, bcat, nullptr, out_mu, out_ls, N, 1);
}

// Round 3
// 380.716 us; speedup vs baseline: 1.9507x; 1.1472x over previous
//
#include <hip/hip_runtime.h>

#define THREADS 256

typedef __attribute__((ext_vector_type(8))) short bf16x8;
typedef __attribute__((ext_vector_type(4))) float f32x4;

#define DEG_SHIFT 44
#define DEG_SCALE 16777216.0f          // 2^24 fixed-point for weighted degree
#define DEG_MASK  ((1ULL << DEG_SHIFT) - 1)

__device__ inline float bf2f(unsigned short u) {
    union { unsigned int i; float f; } v; v.i = ((unsigned int)u) << 16; return v.f;
}
__device__ inline unsigned short f2bf(float f) {
    union { float f; unsigned int i; } v; v.f = f;
    unsigned int i = v.i;
    i += 0x7fff + ((i >> 16) & 1);   // round-to-nearest-even
    return (unsigned short)(i >> 16);
}

// ---------- zero the packed deg/count array ----------
__global__ void k_init(unsigned long long* __restrict__ packed, int n) {
    int i = blockIdx.x * THREADS + threadIdx.x;
    if (i < n) packed[i] = 0ULL;
}

// ---------- one 64-bit atomic per edge: count in [44:63], fixed-point deg in [0:43]
// returned old value gives this edge's rank within its destination (free CSR slot!)
__global__ void k_count(const int* __restrict__ dst, const float* __restrict__ ew,
                        unsigned long long* __restrict__ packed,
                        int* __restrict__ rank, int E) {
    int e = blockIdx.x * THREADS + threadIdx.x;
    if (e >= E) return;
    int c = dst[e];
    unsigned long long v = (1ULL << DEG_SHIFT) |
        (unsigned long long)(ew[e] * DEG_SCALE + 0.5f);
    unsigned long long old = atomicAdd(&packed[c], v);
    rank[e] = (int)(old >> DEG_SHIFT);
}

// ---------- unpack: counts + dinv (deg includes self-loop weight 1) ----------
__global__ void k_unpack(const unsigned long long* __restrict__ packed,
                         int* __restrict__ counts, float* __restrict__ dinv, int n) {
    int i = blockIdx.x * THREADS + threadIdx.x;
    if (i >= n) return;
    unsigned long long p = packed[i];
    counts[i] = (int)(p >> DEG_SHIFT);
    float d = 1.0f + (float)(p & DEG_MASK) * (1.0f / DEG_SCALE);
    dinv[i] = rsqrtf(d);               // d >= 1 always
}

// ---------- exclusive prefix scan over counts ----------
__global__ void k_scan_part(const int* __restrict__ counts, int* __restrict__ offsets,
                            int* __restrict__ blocksum, int n) {
    __shared__ int s[THREADS];
    int i = blockIdx.x * THREADS + threadIdx.x;
    int v = (i < n) ? counts[i] : 0;
    s[threadIdx.x] = v;
    __syncthreads();
    for (int d = 1; d < THREADS; d <<= 1) {
        int t = (threadIdx.x >= d) ? s[threadIdx.x - d] : 0;
        __syncthreads();
        s[threadIdx.x] += t;
        __syncthreads();
    }
    if (i < n) offsets[i] = s[threadIdx.x] - v;
    if (threadIdx.x == THREADS - 1) blocksum[blockIdx.x] = s[THREADS - 1];
}

__global__ void k_scan_block(int* __restrict__ blocksum, int nb) {
    __shared__ int s[THREADS];
    int v = (threadIdx.x < nb) ? blocksum[threadIdx.x] : 0;
    s[threadIdx.x] = v;
    __syncthreads();
    for (int d = 1; d < THREADS; d <<= 1) {
        int t = (threadIdx.x >= d) ? s[threadIdx.x - d] : 0;
        __syncthreads();
        s[threadIdx.x] += t;
        __syncthreads();
    }
    if (threadIdx.x < nb) blocksum[threadIdx.x] = s[threadIdx.x] - v;
}

__global__ void k_scan_add(int* __restrict__ offsets, const int* __restrict__ blocksum, int n) {
    int i = blockIdx.x * THREADS + threadIdx.x;
    if (i >= n) return;
    offsets[i] += blocksum[blockIdx.x];
}

// ---------- CSR fill, atomic-free: pos = offsets[dst] + rank ----------
__global__ void k_fill(const int* __restrict__ ei, const float* __restrict__ ew,
                       const float* __restrict__ dinv, const int* __restrict__ offsets,
                       const int* __restrict__ rank, int2* __restrict__ epack, int E) {
    int e = blockIdx.x * THREADS + threadIdx.x;
    if (e >= E) return;
    int r = ei[e];
    int c = ei[E + e];
    int pos = offsets[c] + rank[e];
    int2 m; m.x = r; m.y = __float_as_int(dinv[r] * ew[e] * dinv[c]);
    epack[pos] = m;
}

// ---------- weight prep: W1 -> W1t[n][k] bf16; [Wmu|Wls] -> Wct[n][k] bf16; bcat
__global__ void k_cvt_w(const float* __restrict__ W1, const float* __restrict__ Wmu,
                        const float* __restrict__ Wls, const float* __restrict__ bmu,
                        const float* __restrict__ bls,
                        ushort* __restrict__ W1t, ushort* __restrict__ Wct,
                        float* __restrict__ bcat) {
    int n = blockIdx.x, k = threadIdx.x;
    if (n < 256) {
        W1t[n * 256 + k] = f2bf(W1[k * 256 + n]);
    } else if (n < 512) {
        int nn = n - 256;
        float v = (nn < 128) ? Wmu[k * 128 + nn] : Wls[k * 128 + (nn - 128)];
        Wct[nn * 256 + k] = f2bf(v);
    } else {
        bcat[k] = (k < 128) ? bmu[k] : bls[k - 128];
    }
}

// ---------- aggregation: out[i] = bias + dinv_i^2*f[i] + sum_e norm_e*f[src_e]
// one wave per node; lane covers 4 features (8 B bf16)
// MODE 0: +bias, relu, bf16 out.  MODE 1: +bias, f32 out split mu/logstd.
template<int MODE>
__global__ void k_agg(const ushort4* __restrict__ fb,
                      const int* __restrict__ eoff, const int* __restrict__ ecnt,
                      const int2* __restrict__ epack, const float* __restrict__ dinv,
                      const float* __restrict__ bias, void* __restrict__ out, int n) {
    int wave = threadIdx.x >> 6, lane = threadIdx.x & 63;
    int node = blockIdx.x * 4 + wave;
    if (node >= n) return;
    float ds = dinv[node]; ds *= ds;        // self-loop norm
    ushort4 v = fb[node * 64 + lane];
    float ax = ds * bf2f(v.x), ay = ds * bf2f(v.y),
          az = ds * bf2f(v.z), aw = ds * bf2f(v.w);
    int e = eoff[node], end = e + ecnt[node];
    for (; e + 4 <= end; e += 4) {
        int2 m0 = epack[e], m1 = epack[e + 1], m2 = epack[e + 2], m3 = epack[e + 3];
        ushort4 u0 = fb[m0.x * 64 + lane];
        ushort4 u1 = fb[m1.x * 64 + lane];
        ushort4 u2 = fb[m2.x * 64 + lane];
        ushort4 u3 = fb[m3.x * 64 + lane];
        float w0 = __int_as_float(m0.y), w1 = __int_as_float(m1.y),
              w2 = __int_as_float(m2.y), w3 = __int_as_float(m3.y);
        ax += w0 * bf2f(u0.x) + w1 * bf2f(u1.x) + w2 * bf2f(u2.x) + w3 * bf2f(u3.x);
        ay += w0 * bf2f(u0.y) + w1 * bf2f(u1.y) + w2 * bf2f(u2.y) + w3 * bf2f(u3.y);
        az += w0 * bf2f(u0.z) + w1 * bf2f(u1.z) + w2 * bf2f(u2.z) + w3 * bf2f(u3.z);
        aw += w0 * bf2f(u0.w) + w1 * bf2f(u1.w) + w2 * bf2f(u2.w) + w3 * bf2f(u3.w);
    }
    for (; e < end; e++) {
        int2 m = epack[e];
        ushort4 u = fb[m.x * 64 + lane];
        float w = __int_as_float(m.y);
        ax += w * bf2f(u.x); ay += w * bf2f(u.y);
        az += w * bf2f(u.z); aw += w * bf2f(u.w);
    }
    float4 b = ((const float4*)bias)[lane];
    ax += b.x; ay += b.y; az += b.z; aw += b.w;
    if (MODE == 0) {
        ushort4 o;
        o.x = f2bf(fmaxf(ax, 0.f)); o.y = f2bf(fmaxf(ay, 0.f));
        o.z = f2bf(fmaxf(az, 0.f)); o.w = f2bf(fmaxf(aw, 0.f));
        ((ushort4*)out)[node * 64 + lane] = o;
    } else {
        float4 o; o.x = ax; o.y = ay; o.z = az; o.w = aw;
        float4* mu = (float4*)out;              // [n][32] float4
        float4* ls = mu + (size_t)n * 32;
        if (lane < 32) mu[node * 32 + lane] = o;
        else           ls[node * 32 + (lane - 32)] = o;
    }
}

// ---------- bf16 MFMA GEMM: C[Mx256] = A[Mx256] @ Bt[256x256]^T, bf16 out, no bias
// AF32: A is f32, converted to bf16 during LDS staging.
#define LDT 40   // padded LDS row stride (ushorts): <=2-way bank aliasing (free, m136)
template<int AF32>
__global__ __launch_bounds__(256) void k_gemm(const void* __restrict__ Ain,
        const ushort* __restrict__ Bt, ushort* __restrict__ C, int M) {
    __shared__ ushort As[128 * LDT];
    __shared__ ushort Bs[128 * LDT];
    const float*  Af = (const float*)Ain;
    const ushort* Ab = (const ushort*)Ain;
    int tid = threadIdx.x;
    int lane = tid & 63, wave = tid >> 6;
    int row0 = blockIdx.y * 128, col0 = blockIdx.x * 128;
    int mw = (wave >> 1) * 64, nw = (wave & 1) * 64;
    int lr = lane & 15, lq = lane >> 4;
    f32x4 acc[4][4] = {};
    for (int k0 = 0; k0 < 256; k0 += 32) {
        #pragma unroll
        for (int i = 0; i < 2; i++) {
            int c = tid + i * 256;          // 0..511 chunks of 8 bf16
            int r = c >> 2, q = c & 3;
            int gr = row0 + r;
            int4 av = make_int4(0, 0, 0, 0);
            if (gr < M) {
                if (AF32) {
                    const float* p = Af + (size_t)gr * 256 + k0 + q * 8;
                    float4 lo = *(const float4*)p;
                    float4 hi = *(const float4*)(p + 4);
                    ushort* u = (ushort*)&av;
                    u[0] = f2bf(lo.x); u[1] = f2bf(lo.y);
                    u[2] = f2bf(lo.z); u[3] = f2bf(lo.w);
                    u[4] = f2bf(hi.x); u[5] = f2bf(hi.y);
                    u[6] = f2bf(hi.z); u[7] = f2bf(hi.w);
                } else {
                    av = *(const int4*)(Ab + (size_t)gr * 256 + k0 + q * 8);
                }
            }
            *(int4*)(&As[r * LDT + q * 8]) = av;
            int4 bv = *(const int4*)(Bt + (size_t)(col0 + r) * 256 + k0 + q * 8);
            *(int4*)(&Bs[r * LDT + q * 8]) = bv;
        }
        __syncthreads();
        bf16x8 af[4], bfr[4];
        #pragma unroll
        for (int mi = 0; mi < 4; mi++)
            af[mi] = *(const bf16x8*)(&As[(mw + mi * 16 + lr) * LDT + lq * 8]);
        #pragma unroll
        for (int ni = 0; ni < 4; ni++)
            bfr[ni] = *(const bf16x8*)(&Bs[(nw + ni * 16 + lr) * LDT + lq * 8]);
        #pragma unroll
        for (int mi = 0; mi < 4; mi++)
            #pragma unroll
            for (int ni = 0; ni < 4; ni++)
                acc[mi][ni] = __builtin_amdgcn_mfma_f32_16x16x32_bf16(
                    af[mi], bfr[ni], acc[mi][ni], 0, 0, 0);
        __syncthreads();
    }
    // C/D layout: col = lane&15, row = (lane>>4)*4 + reg
    #pragma unroll
    for (int mi = 0; mi < 4; mi++)
        #pragma unroll
        for (int ni = 0; ni < 4; ni++)
            #pragma unroll
            for (int r = 0; r < 4; r++) {
                int grow = row0 + mw + mi * 16 + lq * 4 + r;
                int gcol = col0 + nw + ni * 16 + lr;
                if (grow < M) C[(size_t)grow * 256 + gcol] = f2bf(acc[mi][ni][r]);
            }
}

extern "C" void kernel_launch(void* const* d_in, const int* in_sizes, int n_in,
                              void* d_out, int out_size, void* d_ws, size_t ws_size,
                              hipStream_t stream) {
    const float* x   = (const float*)d_in[0];
    const int*   ei  = (const int*)d_in[1];
    const float* ew  = (const float*)d_in[2];
    const float* W1  = (const float*)d_in[3];
    const float* b1  = (const float*)d_in[4];
    const float* Wmu = (const float*)d_in[5];
    const float* bmu = (const float*)d_in[6];
    const float* Wls = (const float*)d_in[7];
    const float* bls = (const float*)d_in[8];

    const int DIN = 256;
    const int N = in_sizes[0] / DIN;
    const int E = in_sizes[2];

    // workspace layout
    unsigned long long* packed = (unsigned long long*)d_ws;   // N
    int*   counts   = (int*)(packed + N);             // N
    int*   offsets  = counts + N;                     // N
    float* dinv     = (float*)(offsets + N);          // N
    int*   blocksum = (int*)(dinv + N);               // 256
    int*   rank     = blocksum + 256;                 // E
    int2*  epack    = (int2*)(rank + E);              // E
    ushort* xw      = (ushort*)(epack + E);           // N*256  (x@W1, bf16)
    ushort* hb      = xw + (size_t)N * 256;           // N*256  (h, bf16)
    ushort* hw      = hb + (size_t)N * 256;           // N*256  (h@Wct, bf16)
    ushort* W1t     = hw + (size_t)N * 256;           // 256*256
    ushort* Wct     = W1t + 256 * 256;                // 256*256
    float*  bcat    = (float*)(Wct + 256 * 256);      // 256

    int gN = (N + THREADS - 1) / THREADS;
    int gE = (E + THREADS - 1) / THREADS;

    k_init<<<gN, THREADS, 0, stream>>>(packed, N);
    k_count<<<gE, THREADS, 0, stream>>>(ei + E, ew, packed, rank, E);
    k_unpack<<<gN, THREADS, 0, stream>>>(packed, counts, dinv, N);

    k_scan_part<<<gN, THREADS, 0, stream>>>(counts, offsets, blocksum, N);
    k_scan_block<<<1, THREADS, 0, stream>>>(blocksum, gN);
    k_scan_add<<<gN, THREADS, 0, stream>>>(offsets, blocksum, N);

    k_fill<<<gE, THREADS, 0, stream>>>(ei, ew, dinv, offsets, rank, epack, E);

    k_cvt_w<<<513, THREADS, 0, stream>>>(W1, Wmu, Wls, bmu, bls, W1t, Wct, bcat);

    int gAgg = (N + 3) / 4;
    dim3 ggrid(2, (N + 127) / 128);

    // layer 1: xw = x@W1 (f32-in GEMM);  h = relu(A_hat@xw + b1)
    k_gemm<1><<<ggrid, 256, 0, stream>>>(x, W1t, xw, N);
    k_agg<0><<<gAgg, THREADS, 0, stream>>>((const ushort4*)xw, offsets, counts,
                                           epack, dinv, b1, hb, N);

    // layer 2: hw = h@[Wmu|Wls];  {mu,logstd} = A_hat@hw + bcat
    k_gemm<0><<<ggrid, 256, 0, stream>>>(hb, Wct, hw, N);
    k_agg<1><<<gAgg, THREADS, 0, stream>>>((const ushort4*)hw, offsets, counts,
                                           epack, dinv, bcat, d_out, N);
}